// Round 18
// baseline (42.880 us; speedup 1.0000x reference)
//
#include <hip/hip_runtime.h>
#include <hip/hip_bf16.h>
#include <math.h>

#define HWV (1080 * 1920)
#define NPIX (2 * HWV)

typedef _Float16 half2 __attribute__((ext_vector_type(2)));
typedef __fp16   pk2   __attribute__((ext_vector_type(2)));
union U32H2 { unsigned u; half2 h; pk2 p; };

// ---------------------------------------------------------------------------
// Prep kernel (8 blocks x 256): fold BN + pack f16 weights; per-column table.
// u32 wp = (unsigned*)(wsw+84):
//   wp[4c+{0,1,2,3}] = {wr,wr},{wg,wg},{wb,wb},{bs,bs}  (c = 0..15)
//   wp[64+c] = {w2c,w2c}   wp[80] = {b2,b2}
// colinfo (uint4, at wsw+168): per column x:
//   .x = x0 | (x1<<8)   .y = {wx0,wx0} f16   .z = {wx1,wx1} f16
// ---------------------------------------------------------------------------
__global__ void prep_w(const float* __restrict__ w1, const float* __restrict__ b1,
                       const float* __restrict__ gamma, const float* __restrict__ beta,
                       const float* __restrict__ mean, const float* __restrict__ var,
                       const float* __restrict__ w2, const float* __restrict__ b2,
                       float* __restrict__ wsw) {
    int i = blockIdx.x * blockDim.x + threadIdx.x;
    unsigned* wp = (unsigned*)(wsw + 84);
    if (i < 16) {
        float inv = gamma[i] / sqrtf(var[i] + 1e-5f);
        float wr = w1[i*3+0] * inv, wg = w1[i*3+1] * inv, wb = w1[i*3+2] * inv;
        float bs = (b1[i] - mean[i]) * inv + beta[i];
        U32H2 t;
        t.p = __builtin_amdgcn_cvt_pkrtz(wr, wr); wp[i*4+0] = t.u;
        t.p = __builtin_amdgcn_cvt_pkrtz(wg, wg); wp[i*4+1] = t.u;
        t.p = __builtin_amdgcn_cvt_pkrtz(wb, wb); wp[i*4+2] = t.u;
        t.p = __builtin_amdgcn_cvt_pkrtz(bs, bs); wp[i*4+3] = t.u;
        float w2c = w2[i];
        t.p = __builtin_amdgcn_cvt_pkrtz(w2c, w2c); wp[64 + i] = t.u;
    }
    if (i == 16) {
        float b2s = b2[0];
        U32H2 t;
        t.p = __builtin_amdgcn_cvt_pkrtz(b2s, b2s); wp[80] = t.u;
    }
    if (i < 1920) {
        float gx = (float)i * (15.0f / 1919.0f);
        float x0f = floorf(gx);
        float tx = gx - x0f;
        int x0 = (int)x0f;
        int x1 = min(x0 + 1, 15);
        U32H2 a0, a1;
        a0.p = __builtin_amdgcn_cvt_pkrtz(1.0f - tx, 1.0f - tx);
        a1.p = __builtin_amdgcn_cvt_pkrtz(tx, tx);
        uint4* colinfo = (uint4*)(wsw + 168);
        colinfo[i] = make_uint4((unsigned)(x0 | (x1 << 8)), a0.u, a1.u, 0u);
    }
}

// ---------------------------------------------------------------------------
// Kernel A: guide net only. 4 px/thread, float4 I/O, fully-packed f16 MLP.
// Output: u16 fixed-point gz*4096 (z0 = u>>12, tz = (u&4095)/4096).
// Pure streaming, no gather -> near-BW-bound.
// ---------------------------------------------------------------------------
__global__ __launch_bounds__(256) void guide_kernel(
        const float* __restrict__ fullres,
        const float* __restrict__ wsw,
        unsigned short* __restrict__ gp) {
    int i = blockIdx.x * 256 + threadIdx.x;     // 4050*256 = NPIX/4 exactly
    int n  = i / (HWV / 4);
    int pi = (i - n * (HWV / 4)) * 4;
    const float* fr = fullres + n * 3 * HWV + pi;
    float4 R = *(const float4*)(fr);
    float4 G = *(const float4*)(fr + HWV);
    float4 B = *(const float4*)(fr + 2 * HWV);

    U32H2 r01, r23, g01, g23, b01, b23;
    r01.p = __builtin_amdgcn_cvt_pkrtz(R.x, R.y);
    r23.p = __builtin_amdgcn_cvt_pkrtz(R.z, R.w);
    g01.p = __builtin_amdgcn_cvt_pkrtz(G.x, G.y);
    g23.p = __builtin_amdgcn_cvt_pkrtz(G.z, G.w);
    b01.p = __builtin_amdgcn_cvt_pkrtz(B.x, B.y);
    b23.p = __builtin_amdgcn_cvt_pkrtz(B.z, B.w);
    const unsigned* wp = (const unsigned*)(wsw + 84);
    const half2 zero = {(_Float16)0.0f, (_Float16)0.0f};
    U32H2 acc01, acc23;
    acc01.u = wp[80];
    acc23.u = wp[80];
#pragma unroll
    for (int c = 0; c < 16; ++c) {
        U32H2 wr, wg, wb, bs, w2d;
        wr.u = wp[4*c+0]; wg.u = wp[4*c+1]; wb.u = wp[4*c+2]; bs.u = wp[4*c+3];
        w2d.u = wp[64 + c];
        half2 h01 = wr.h * r01.h + (wg.h * g01.h + (wb.h * b01.h + bs.h));
        half2 h23 = wr.h * r23.h + (wg.h * g23.h + (wb.h * b23.h + bs.h));
        h01 = __builtin_elementwise_max(h01, zero);
        h23 = __builtin_elementwise_max(h23, zero);
        acc01.h = h01 * w2d.h + acc01.h;
        acc23.h = h23 * w2d.h + acc23.h;
    }
    float accv[4] = {(float)acc01.h.x, (float)acc01.h.y,
                     (float)acc23.h.x, (float)acc23.h.y};
    unsigned short us[4];
#pragma unroll
    for (int q = 0; q < 4; ++q) {
        float e = __expf(-accv[q]);
        float guide = __builtin_amdgcn_rcpf(1.0f + e);
        us[q] = (unsigned short)(guide * 28672.0f);   // 7 * 4096
    }
    ushort4 o = make_ushort4(us[0], us[1], us[2], us[3]);
    *(ushort4*)(gp + n * HWV + pi) = o;
}

// ---------------------------------------------------------------------------
// Kernel B: slice + apply (R17 core minus MLP). 512 thr x 2 px; chain starts
// at a coalesced u16 load instead of MLP+exp. fullres re-read is L3-hot.
// ---------------------------------------------------------------------------
__global__ __launch_bounds__(512, 8) void slice_kernel(
        const float* __restrict__ fullres,
        const float* __restrict__ grid,
        const float* __restrict__ wsw,
        const unsigned short* __restrict__ gp,
        float* __restrict__ out) {
    __shared__ unsigned slo[9][9][4];
    __shared__ unsigned shi[9][9][2];

    const int tid = threadIdx.x;
    const int seg = blockIdx.x;
    const int n   = blockIdx.y;
    const int y   = blockIdx.z;
    const int xs  = seg * 1024;
    const int x   = xs + 2 * tid;
    const bool act = (x < 1920);
    const int a = (int)((float)xs * (15.0f / 1919.0f));
    const int pcol = min(x, 1918);
    const int p = y * 1920 + pcol;

    const float* fr = fullres + n * 3 * HWV + p;
    float2 R = *(const float2*)(fr);
    float2 G = *(const float2*)(fr + HWV);
    float2 B = *(const float2*)(fr + 2 * HWV);
    unsigned gpu = *(const unsigned*)(gp + n * HWV + p);
    const uint4* colinfo = (const uint4*)(wsw + 168);
    uint4 ci0 = colinfo[pcol];
    uint4 ci1 = colinfo[pcol + 1];

    if (tid < 486) {
        float gy = (float)y * (15.0f / 1079.0f);
        float y0f = floorf(gy);
        float ty = gy - y0f;
        int y0 = min((int)y0f, 15);
        int y1 = min(y0 + 1, 15);
        const int dy = (y1 - y0) * 16;
        int j   = tid / 81;
        int rem = tid - j * 81;
        int z   = rem / 9;
        int k   = rem - z * 9;
        int zz  = min(z, 7);
        int xc  = min(a + k, 15);
        const float* q0 = grid + n * 24576 + (2 * j) * 2048 + zz * 256 + y0 * 16 + xc;
        const float* q1 = q0 + 2048;
        float v00 = q0[0], v01 = q0[dy];
        float v10 = q1[0], v11 = q1[dy];
        float e0 = fmaf(ty, v01 - v00, v00);
        float e1 = fmaf(ty, v11 - v10, v10);
        U32H2 t;
        t.p = __builtin_amdgcn_cvt_pkrtz(e0, e1);
        if (j < 4) slo[k][z][j] = t.u;
        else       shi[k][z][j - 4] = t.u;
    }
    __syncthreads();

    if (!act) return;

    float rv[2] = {R.x, R.y}, gv[2] = {G.x, G.y}, bv[2] = {B.x, B.y};
    float outr[2], outg[2], outb[2];
    uint4 civ[2] = {ci0, ci1};

#pragma unroll
    for (int q = 0; q < 2; ++q) {
        unsigned u = (q == 0) ? (gpu & 0xFFFFu) : (gpu >> 16);
        int z0 = (int)(u >> 12);            // 0..7
        int z1 = z0 + 1;                    // slot 8 duplicates z=7
        float tz = (float)(u & 4095u) * (1.0f / 4096.0f);

        int k0 = (int)(civ[q].x & 255u) - a;
        int k1 = (int)((civ[q].x >> 8) & 255u) - a;
        U32H2 wx0d, wx1d;
        wx0d.u = civ[q].y;
        wx1d.u = civ[q].z;

        U32H2 wz0d, wz1d;
        wz0d.p = __builtin_amdgcn_cvt_pkrtz(1.0f - tz, 1.0f - tz);
        wz1d.p = __builtin_amdgcn_cvt_pkrtz(tz, tz);

        half2 w00 = wx0d.h * wz0d.h;
        half2 w01 = wx0d.h * wz1d.h;
        half2 w10 = wx1d.h * wz0d.h;
        half2 w11 = wx1d.h * wz1d.h;

        const uint4 A0 = *(const uint4*)&slo[k0][z0][0];
        const uint4 A1 = *(const uint4*)&slo[k0][z1][0];
        const uint4 B0 = *(const uint4*)&slo[k1][z0][0];
        const uint4 B1 = *(const uint4*)&slo[k1][z1][0];
        const uint2 C0 = *(const uint2*)&shi[k0][z0][0];
        const uint2 C1 = *(const uint2*)&shi[k0][z1][0];
        const uint2 D0 = *(const uint2*)&shi[k1][z0][0];
        const uint2 D1 = *(const uint2*)&shi[k1][z1][0];

        unsigned a0j[6] = {A0.x, A0.y, A0.z, A0.w, C0.x, C0.y};
        unsigned a1j[6] = {A1.x, A1.y, A1.z, A1.w, C1.x, C1.y};
        unsigned b0j[6] = {B0.x, B0.y, B0.z, B0.w, D0.x, D0.y};
        unsigned b1j[6] = {B1.x, B1.y, B1.z, B1.w, D1.x, D1.y};

        half2 hc[6];
#pragma unroll
        for (int j = 0; j < 6; ++j) {
            U32H2 ua0, ua1, ub0, ub1;
            ua0.u = a0j[j]; ua1.u = a1j[j]; ub0.u = b0j[j]; ub1.u = b1j[j];
            half2 h = w00 * ua0.h + (w01 * ua1.h);
            h = w10 * ub0.h + h;
            h = w11 * ub1.h + h;
            hc[j] = h;
        }

        outr[q] = fmaf((float)hc[0].x, rv[q], fmaf((float)hc[0].y, gv[q],
                  fmaf((float)hc[1].x, bv[q], (float)hc[1].y)));
        outg[q] = fmaf((float)hc[2].x, rv[q], fmaf((float)hc[2].y, gv[q],
                  fmaf((float)hc[3].x, bv[q], (float)hc[3].y)));
        outb[q] = fmaf((float)hc[4].x, rv[q], fmaf((float)hc[4].y, gv[q],
                  fmaf((float)hc[5].x, bv[q], (float)hc[5].y)));
    }

    float* op = out + n * 3 * HWV + p;
    *(float2*)(op)           = make_float2(outr[0], outr[1]);
    *(float2*)(op + HWV)     = make_float2(outg[0], outg[1]);
    *(float2*)(op + 2 * HWV) = make_float2(outb[0], outb[1]);
}

// ---------------------------------------------------------------------------
// Fallback: R17 single fused kernel (used if ws_size can't hold the guide buf)
// ---------------------------------------------------------------------------
__global__ __launch_bounds__(512, 8) void fused_kernel(
        const float* __restrict__ fullres,
        const float* __restrict__ grid,
        const float* __restrict__ wsw,
        float* __restrict__ out) {
    __shared__ unsigned slo[9][9][4];
    __shared__ unsigned shi[9][9][2];

    const int tid = threadIdx.x;
    const int seg = blockIdx.x;
    const int n   = blockIdx.y;
    const int y   = blockIdx.z;
    const int xs  = seg * 1024;
    const int x   = xs + 2 * tid;
    const bool act = (x < 1920);
    const int a = (int)((float)xs * (15.0f / 1919.0f));
    const int pcol = min(x, 1918);
    const int p = y * 1920 + pcol;

    const float* fr = fullres + n * 3 * HWV + p;
    float2 R = *(const float2*)(fr);
    float2 G = *(const float2*)(fr + HWV);
    float2 B = *(const float2*)(fr + 2 * HWV);
    const uint4* colinfo = (const uint4*)(wsw + 168);
    uint4 ci0 = colinfo[pcol];
    uint4 ci1 = colinfo[pcol + 1];

    if (tid < 486) {
        float gy = (float)y * (15.0f / 1079.0f);
        float y0f = floorf(gy);
        float ty = gy - y0f;
        int y0 = min((int)y0f, 15);
        int y1 = min(y0 + 1, 15);
        const int dy = (y1 - y0) * 16;
        int j   = tid / 81;
        int rem = tid - j * 81;
        int z   = rem / 9;
        int k   = rem - z * 9;
        int zz  = min(z, 7);
        int xc  = min(a + k, 15);
        const float* q0 = grid + n * 24576 + (2 * j) * 2048 + zz * 256 + y0 * 16 + xc;
        const float* q1 = q0 + 2048;
        float v00 = q0[0], v01 = q0[dy];
        float v10 = q1[0], v11 = q1[dy];
        float e0 = fmaf(ty, v01 - v00, v00);
        float e1 = fmaf(ty, v11 - v10, v10);
        U32H2 t;
        t.p = __builtin_amdgcn_cvt_pkrtz(e0, e1);
        if (j < 4) slo[k][z][j] = t.u;
        else       shi[k][z][j - 4] = t.u;
    }
    __syncthreads();

    if (!act) return;

    U32H2 rr, gg, bb;
    rr.p = __builtin_amdgcn_cvt_pkrtz(R.x, R.y);
    gg.p = __builtin_amdgcn_cvt_pkrtz(G.x, G.y);
    bb.p = __builtin_amdgcn_cvt_pkrtz(B.x, B.y);
    const unsigned* wp = (const unsigned*)(wsw + 84);
    const half2 zero = {(_Float16)0.0f, (_Float16)0.0f};
    U32H2 accp; accp.u = wp[80];
#pragma unroll
    for (int c = 0; c < 16; ++c) {
        U32H2 wr, wg, wb, bs, w2d;
        wr.u = wp[4*c+0]; wg.u = wp[4*c+1]; wb.u = wp[4*c+2]; bs.u = wp[4*c+3];
        w2d.u = wp[64 + c];
        half2 h = wr.h * rr.h + (wg.h * gg.h + (wb.h * bb.h + bs.h));
        h = __builtin_elementwise_max(h, zero);
        accp.h = h * w2d.h + accp.h;
    }
    float accv[2] = {(float)accp.h.x, (float)accp.h.y};

    float rv[2] = {R.x, R.y}, gv[2] = {G.x, G.y}, bv[2] = {B.x, B.y};
    float outr[2], outg[2], outb[2];
    uint4 civ[2] = {ci0, ci1};

#pragma unroll
    for (int q = 0; q < 2; ++q) {
        float e = __expf(-accv[q]);
        float guide = __builtin_amdgcn_rcpf(1.0f + e);
        float gz = guide * 7.0f;
        float z0f = floorf(gz);
        float tz = gz - z0f;
        int z0 = min((int)z0f, 7);
        int z1 = z0 + 1;

        int k0 = (int)(civ[q].x & 255u) - a;
        int k1 = (int)((civ[q].x >> 8) & 255u) - a;
        U32H2 wx0d, wx1d;
        wx0d.u = civ[q].y;
        wx1d.u = civ[q].z;

        U32H2 wz0d, wz1d;
        wz0d.p = __builtin_amdgcn_cvt_pkrtz(1.0f - tz, 1.0f - tz);
        wz1d.p = __builtin_amdgcn_cvt_pkrtz(tz, tz);

        half2 w00 = wx0d.h * wz0d.h;
        half2 w01 = wx0d.h * wz1d.h;
        half2 w10 = wx1d.h * wz0d.h;
        half2 w11 = wx1d.h * wz1d.h;

        const uint4 A0 = *(const uint4*)&slo[k0][z0][0];
        const uint4 A1 = *(const uint4*)&slo[k0][z1][0];
        const uint4 B0 = *(const uint4*)&slo[k1][z0][0];
        const uint4 B1 = *(const uint4*)&slo[k1][z1][0];
        const uint2 C0 = *(const uint2*)&shi[k0][z0][0];
        const uint2 C1 = *(const uint2*)&shi[k0][z1][0];
        const uint2 D0 = *(const uint2*)&shi[k1][z0][0];
        const uint2 D1 = *(const uint2*)&shi[k1][z1][0];

        unsigned a0j[6] = {A0.x, A0.y, A0.z, A0.w, C0.x, C0.y};
        unsigned a1j[6] = {A1.x, A1.y, A1.z, A1.w, C1.x, C1.y};
        unsigned b0j[6] = {B0.x, B0.y, B0.z, B0.w, D0.x, D0.y};
        unsigned b1j[6] = {B1.x, B1.y, B1.z, B1.w, D1.x, D1.y};

        half2 hc[6];
#pragma unroll
        for (int j = 0; j < 6; ++j) {
            U32H2 ua0, ua1, ub0, ub1;
            ua0.u = a0j[j]; ua1.u = a1j[j]; ub0.u = b0j[j]; ub1.u = b1j[j];
            half2 h = w00 * ua0.h + (w01 * ua1.h);
            h = w10 * ub0.h + h;
            h = w11 * ub1.h + h;
            hc[j] = h;
        }

        outr[q] = fmaf((float)hc[0].x, rv[q], fmaf((float)hc[0].y, gv[q],
                  fmaf((float)hc[1].x, bv[q], (float)hc[1].y)));
        outg[q] = fmaf((float)hc[2].x, rv[q], fmaf((float)hc[2].y, gv[q],
                  fmaf((float)hc[3].x, bv[q], (float)hc[3].y)));
        outb[q] = fmaf((float)hc[4].x, rv[q], fmaf((float)hc[4].y, gv[q],
                  fmaf((float)hc[5].x, bv[q], (float)hc[5].y)));
    }

    float* op = out + n * 3 * HWV + p;
    *(float2*)(op)           = make_float2(outr[0], outr[1]);
    *(float2*)(op + HWV)     = make_float2(outg[0], outg[1]);
    *(float2*)(op + 2 * HWV) = make_float2(outb[0], outb[1]);
}

extern "C" void kernel_launch(void* const* d_in, const int* in_sizes, int n_in,
                              void* d_out, int out_size, void* d_ws, size_t ws_size,
                              hipStream_t stream) {
    const float* fullres = (const float*)d_in[0];
    const float* grid    = (const float*)d_in[1];
    const float* w1      = (const float*)d_in[2];
    const float* b1      = (const float*)d_in[3];
    const float* gamma   = (const float*)d_in[4];
    const float* beta    = (const float*)d_in[5];
    const float* mean    = (const float*)d_in[6];
    const float* var     = (const float*)d_in[7];
    const float* w2      = (const float*)d_in[8];
    const float* b2      = (const float*)d_in[9];
    float* out = (float*)d_out;

    float* wsw = (float*)d_ws;   // 168 floats + 1920 uint4 column table

    prep_w<<<8, 256, 0, stream>>>(w1, b1, gamma, beta, mean, var, w2, b2, wsw);

    const size_t GP_OFF = 65536;                       // bytes, past wsw region
    const size_t need   = GP_OFF + (size_t)NPIX * 2;   // ~8.36 MB

    if (ws_size >= need) {
        unsigned short* gp = (unsigned short*)((char*)d_ws + GP_OFF);
        guide_kernel<<<NPIX / 4 / 256, 256, 0, stream>>>(fullres, wsw, gp);
        dim3 grid_dim(2, 2, 1080);
        slice_kernel<<<grid_dim, 512, 0, stream>>>(fullres, grid, wsw, gp, out);
    } else {
        dim3 grid_dim(2, 2, 1080);
        fused_kernel<<<grid_dim, 512, 0, stream>>>(fullres, grid, wsw, out);
    }
}

// Round 19
// 30.993 us; speedup vs baseline: 1.3835x; 1.3835x over previous
//
#include <hip/hip_runtime.h>
#include <hip/hip_bf16.h>
#include <math.h>

#define HWV (1080 * 1920)

typedef _Float16 half2 __attribute__((ext_vector_type(2)));
typedef __fp16   pk2   __attribute__((ext_vector_type(2)));
union U32H2 { unsigned u; half2 h; pk2 p; };

// ---------------------------------------------------------------------------
// Prep kernel (8 blocks x 256): fold BN + pack f16 weights; per-column table.
// u32 wp = (unsigned*)(wsw+84):
//   wp[4c+{0,1,2,3}] = {wr,wr},{wg,wg},{wb,wb},{bs,bs}  (c = 0..15)
//   wp[64+c] = {w2c,w2c}   wp[80] = {b2,b2}
// colinfo (uint4, at wsw+168): per column x:
//   .x = x0 | (x1<<8)   .y = {wx0,wx0} f16   .z = {wx1,wx1} f16
// ---------------------------------------------------------------------------
__global__ void prep_w(const float* __restrict__ w1, const float* __restrict__ b1,
                       const float* __restrict__ gamma, const float* __restrict__ beta,
                       const float* __restrict__ mean, const float* __restrict__ var,
                       const float* __restrict__ w2, const float* __restrict__ b2,
                       float* __restrict__ wsw) {
    int i = blockIdx.x * blockDim.x + threadIdx.x;
    unsigned* wp = (unsigned*)(wsw + 84);
    if (i < 16) {
        float inv = gamma[i] / sqrtf(var[i] + 1e-5f);
        float wr = w1[i*3+0] * inv, wg = w1[i*3+1] * inv, wb = w1[i*3+2] * inv;
        float bs = (b1[i] - mean[i]) * inv + beta[i];
        U32H2 t;
        t.p = __builtin_amdgcn_cvt_pkrtz(wr, wr); wp[i*4+0] = t.u;
        t.p = __builtin_amdgcn_cvt_pkrtz(wg, wg); wp[i*4+1] = t.u;
        t.p = __builtin_amdgcn_cvt_pkrtz(wb, wb); wp[i*4+2] = t.u;
        t.p = __builtin_amdgcn_cvt_pkrtz(bs, bs); wp[i*4+3] = t.u;
        float w2c = w2[i];
        t.p = __builtin_amdgcn_cvt_pkrtz(w2c, w2c); wp[64 + i] = t.u;
    }
    if (i == 16) {
        float b2s = b2[0];
        U32H2 t;
        t.p = __builtin_amdgcn_cvt_pkrtz(b2s, b2s); wp[80] = t.u;
    }
    if (i < 1920) {
        float gx = (float)i * (15.0f / 1919.0f);
        float x0f = floorf(gx);
        float tx = gx - x0f;
        int x0 = (int)x0f;
        int x1 = min(x0 + 1, 15);
        U32H2 a0, a1;
        a0.p = __builtin_amdgcn_cvt_pkrtz(1.0f - tx, 1.0f - tx);
        a1.p = __builtin_amdgcn_cvt_pkrtz(tx, tx);
        uint4* colinfo = (uint4*)(wsw + 168);
        colinfo[i] = make_uint4((unsigned)(x0 | (x1 << 8)), a0.u, a1.u, 0u);
    }
}

// ---------------------------------------------------------------------------
// Fused kernel (R17, best measured: 31.0 us). Block = 512 threads, 2 px/thread,
// 1024-px x-segment of one row. Stage y-lerped f16 channel-pair slab from
// original grid layout (z=7 dup into slot 8). Guide MLP fully packed f16
// (layer 2 in pk_fma). Per-column x-data from the precomputed table.
// ---------------------------------------------------------------------------
__global__ __launch_bounds__(512, 8) void fused_kernel(
        const float* __restrict__ fullres,
        const float* __restrict__ grid,
        const float* __restrict__ wsw,
        float* __restrict__ out) {
    __shared__ unsigned slo[9][9][4];   // [cell][z][ch-pairs 0..3]
    __shared__ unsigned shi[9][9][2];   // [cell][z][ch-pairs 4..5]

    const int tid = threadIdx.x;
    const int seg = blockIdx.x;
    const int n   = blockIdx.y;
    const int y   = blockIdx.z;
    const int xs  = seg * 1024;
    const int x   = xs + 2 * tid;
    const bool act = (x < 1920);
    const int a = (int)((float)xs * (15.0f / 1919.0f));
    const int pcol = min(x, 1918);
    const int p = y * 1920 + pcol;

    // ---- prefetch fullres + column table (latency hides under staging) ----
    const float* fr = fullres + n * 3 * HWV + p;
    float2 R = *(const float2*)(fr);
    float2 G = *(const float2*)(fr + HWV);
    float2 B = *(const float2*)(fr + 2 * HWV);
    const uint4* colinfo = (const uint4*)(wsw + 168);
    uint4 ci0 = colinfo[pcol];
    uint4 ci1 = colinfo[pcol + 1];

    // ---- stage: 9 cells x 9 z x 6 ch-pairs from original layout ----
    if (tid < 486) {
        float gy = (float)y * (15.0f / 1079.0f);
        float y0f = floorf(gy);
        float ty = gy - y0f;
        int y0 = min((int)y0f, 15);
        int y1 = min(y0 + 1, 15);
        const int dy = (y1 - y0) * 16;
        int j   = tid / 81;           // ch-pair 0..5
        int rem = tid - j * 81;
        int z   = rem / 9;            // 0..8
        int k   = rem - z * 9;        // cell 0..8
        int zz  = min(z, 7);
        int xc  = min(a + k, 15);
        const float* q0 = grid + n * 24576 + (2 * j) * 2048 + zz * 256 + y0 * 16 + xc;
        const float* q1 = q0 + 2048;
        float v00 = q0[0], v01 = q0[dy];
        float v10 = q1[0], v11 = q1[dy];
        float e0 = fmaf(ty, v01 - v00, v00);
        float e1 = fmaf(ty, v11 - v10, v10);
        U32H2 t;
        t.p = __builtin_amdgcn_cvt_pkrtz(e0, e1);
        if (j < 4) slo[k][z][j] = t.u;
        else       shi[k][z][j - 4] = t.u;
    }
    __syncthreads();

    if (!act) return;

    // ---- guide MLP: fully packed f16 (both px in one half2 lane) ----
    U32H2 rr, gg, bb;
    rr.p = __builtin_amdgcn_cvt_pkrtz(R.x, R.y);
    gg.p = __builtin_amdgcn_cvt_pkrtz(G.x, G.y);
    bb.p = __builtin_amdgcn_cvt_pkrtz(B.x, B.y);
    const unsigned* wp = (const unsigned*)(wsw + 84);
    const half2 zero = {(_Float16)0.0f, (_Float16)0.0f};
    U32H2 accp; accp.u = wp[80];
#pragma unroll
    for (int c = 0; c < 16; ++c) {
        U32H2 wr, wg, wb, bs, w2d;
        wr.u = wp[4*c+0]; wg.u = wp[4*c+1]; wb.u = wp[4*c+2]; bs.u = wp[4*c+3];
        w2d.u = wp[64 + c];
        half2 h = wr.h * rr.h + (wg.h * gg.h + (wb.h * bb.h + bs.h));
        h = __builtin_elementwise_max(h, zero);
        accp.h = h * w2d.h + accp.h;
    }
    float accv[2] = {(float)accp.h.x, (float)accp.h.y};

    float rv[2] = {R.x, R.y}, gv[2] = {G.x, G.y}, bv[2] = {B.x, B.y};
    float outr[2], outg[2], outb[2];
    uint4 civ[2] = {ci0, ci1};

#pragma unroll
    for (int q = 0; q < 2; ++q) {
        float e = __expf(-accv[q]);
        float guide = __builtin_amdgcn_rcpf(1.0f + e);
        float gz = guide * 7.0f;
        float z0f = floorf(gz);
        float tz = gz - z0f;
        int z0 = min((int)z0f, 7);
        int z1 = z0 + 1;               // slot 8 duplicates z=7

        // per-column data from table
        int k0 = (int)(civ[q].x & 255u) - a;
        int k1 = (int)((civ[q].x >> 8) & 255u) - a;
        U32H2 wx0d, wx1d;
        wx0d.u = civ[q].y;
        wx1d.u = civ[q].z;

        U32H2 wz0d, wz1d;
        wz0d.p = __builtin_amdgcn_cvt_pkrtz(1.0f - tz, 1.0f - tz);
        wz1d.p = __builtin_amdgcn_cvt_pkrtz(tz, tz);

        half2 w00 = wx0d.h * wz0d.h;
        half2 w01 = wx0d.h * wz1d.h;
        half2 w10 = wx1d.h * wz0d.h;
        half2 w11 = wx1d.h * wz1d.h;

        const uint4 A0 = *(const uint4*)&slo[k0][z0][0];
        const uint4 A1 = *(const uint4*)&slo[k0][z1][0];
        const uint4 B0 = *(const uint4*)&slo[k1][z0][0];
        const uint4 B1 = *(const uint4*)&slo[k1][z1][0];
        const uint2 C0 = *(const uint2*)&shi[k0][z0][0];
        const uint2 C1 = *(const uint2*)&shi[k0][z1][0];
        const uint2 D0 = *(const uint2*)&shi[k1][z0][0];
        const uint2 D1 = *(const uint2*)&shi[k1][z1][0];

        unsigned a0j[6] = {A0.x, A0.y, A0.z, A0.w, C0.x, C0.y};
        unsigned a1j[6] = {A1.x, A1.y, A1.z, A1.w, C1.x, C1.y};
        unsigned b0j[6] = {B0.x, B0.y, B0.z, B0.w, D0.x, D0.y};
        unsigned b1j[6] = {B1.x, B1.y, B1.z, B1.w, D1.x, D1.y};

        half2 hc[6];
#pragma unroll
        for (int j = 0; j < 6; ++j) {
            U32H2 ua0, ua1, ub0, ub1;
            ua0.u = a0j[j]; ua1.u = a1j[j]; ub0.u = b0j[j]; ub1.u = b1j[j];
            half2 h = w00 * ua0.h + (w01 * ua1.h);
            h = w10 * ub0.h + h;
            h = w11 * ub1.h + h;
            hc[j] = h;
        }

        outr[q] = fmaf((float)hc[0].x, rv[q], fmaf((float)hc[0].y, gv[q],
                  fmaf((float)hc[1].x, bv[q], (float)hc[1].y)));
        outg[q] = fmaf((float)hc[2].x, rv[q], fmaf((float)hc[2].y, gv[q],
                  fmaf((float)hc[3].x, bv[q], (float)hc[3].y)));
        outb[q] = fmaf((float)hc[4].x, rv[q], fmaf((float)hc[4].y, gv[q],
                  fmaf((float)hc[5].x, bv[q], (float)hc[5].y)));
    }

    float* op = out + n * 3 * HWV + p;
    *(float2*)(op)           = make_float2(outr[0], outr[1]);
    *(float2*)(op + HWV)     = make_float2(outg[0], outg[1]);
    *(float2*)(op + 2 * HWV) = make_float2(outb[0], outb[1]);
}

extern "C" void kernel_launch(void* const* d_in, const int* in_sizes, int n_in,
                              void* d_out, int out_size, void* d_ws, size_t ws_size,
                              hipStream_t stream) {
    const float* fullres = (const float*)d_in[0];
    const float* grid    = (const float*)d_in[1];
    const float* w1      = (const float*)d_in[2];
    const float* b1      = (const float*)d_in[3];
    const float* gamma   = (const float*)d_in[4];
    const float* beta    = (const float*)d_in[5];
    const float* mean    = (const float*)d_in[6];
    const float* var     = (const float*)d_in[7];
    const float* w2      = (const float*)d_in[8];
    const float* b2      = (const float*)d_in[9];
    float* out = (float*)d_out;

    float* wsw = (float*)d_ws;   // 168 floats + 1920 uint4 column table

    prep_w<<<8, 256, 0, stream>>>(w1, b1, gamma, beta, mean, var, w2, b2, wsw);

    dim3 grid_dim(2, 2, 1080);   // seg x img x row = 4320 blocks of 512
    fused_kernel<<<grid_dim, 512, 0, stream>>>(fullres, grid, wsw, out);
}